// Round 7
// baseline (193.575 us; speedup 1.0000x reference)
//
#include <hip/hip_runtime.h>
#include <hip/hip_bf16.h>
#include <stdint.h>

// Problem constants
#define B_N     2048
#define E_N     32
#define IN_N    2048
#define OUT_N   1024
#define TOPK    4

// GEMM tiling
#define BM      320                 // rows per item (1 tile/expert for c_e<=320)
#define BN      128                 // cols per item -> 8 nt
#define BK      64
#define NKT     (IN_N / BK)         // 32 k-steps
#define THREADS 512                 // 8 waves: 4m x 2n, wave tile 80x64
#define GRID_GEMM 256

// LDS geometry (uint4 slots): A 320x8, W 128x8, per-buf 3584, dbuf
#define ASLOTS  2560
#define WBASE   2560
#define BUFSTRIDE 3584

// ws int layout
#define WS_COUNTS 0      // [32]
#define WS_QCUR   32     // [8]
#define WS_QLEN   40     // [8]
#define WS_QUEUE  64     // [8][512]
#define WS_LISTS  4160   // [E_N][B_N] packed (b<<2)|k
#define FEATB_OFF 278784 // bytes; bf16 feat copy (8MB)

// s_getreg encoding: id=20 (HW_REG_XCC_ID), offset=0, size=4
#define XCC_ENC (20 | (0 << 6) | (3 << 11))

typedef float  f32x4  __attribute__((ext_vector_type(4)));
typedef __bf16 bf16x8 __attribute__((ext_vector_type(8)));

union Pack8 { bf16x8 v; uint4 u; };

__device__ __forceinline__ uint4 pack8(f32x4 lo, f32x4 hi) {
  Pack8 p;
#pragma unroll
  for (int j = 0; j < 4; ++j) { p.v[j] = (__bf16)lo[j]; p.v[j + 4] = (__bf16)hi[j]; }
  return p.u;
}
__device__ __forceinline__ bf16x8 as_frag(uint4 u) { Pack8 p; p.u = u; return p.v; }

// ---------------- kernel 0: zero counters/cursors ----------------
__global__ void k_zero(int* __restrict__ ws) {
  if (threadIdx.x < 64) ws[threadIdx.x] = 0;
}

// ---------------- kernel 0b: feat f32 -> bf16 ----------------
__global__ void k_conv(const float* __restrict__ f, unsigned short* __restrict__ o) {
  int i = (blockIdx.x * 256 + threadIdx.x) * 8;
  f32x4 a = *(const f32x4*)(f + i);
  f32x4 b = *(const f32x4*)(f + i + 4);
  *(uint4*)(o + i) = pack8(a, b);
}

// ---------------- kernel 1: top-4-smallest + bucket ----------------
__global__ void k_topk(const float* __restrict__ act, int* __restrict__ ws) {
  int b = blockIdx.x * blockDim.x + threadIdx.x;
  if (b >= B_N) return;
  float v[E_N];
  const float* a = act + (size_t)b * E_N;
#pragma unroll
  for (int e = 0; e < E_N; ++e) v[e] = a[e];
  unsigned chosen = 0;
#pragma unroll
  for (int k = 0; k < TOPK; ++k) {
    float mv = 3.4e38f; int mi = 0;
#pragma unroll
    for (int e = 0; e < E_N; ++e) {
      bool sel = (((chosen >> e) & 1u) == 0u) && (v[e] < mv);  // strict <: stable
      mv = sel ? v[e] : mv;
      mi = sel ? e : mi;
    }
    chosen |= (1u << mi);
    int pos = atomicAdd(&ws[WS_COUNTS + mi], 1);
    ws[WS_LISTS + mi * B_N + pos] = (b << 2) | k;
  }
}

// ---------------- kernel 2: build per-XCD work queues ----------------
// queue q holds experts e with e%8==q; the 8 nt-items of an expert adjacent
// so they are popped by 8 CUs of ONE XCD concurrently (A L2-sharing).
// item = (e<<8)|(mt<<3)|nt ; mt>=1 tiles (pathological inputs) appended last.
__global__ void k_tiles(int* __restrict__ ws) {
  int e = threadIdx.x;  // one wave of 64
  int c = (e < E_N) ? ws[WS_COUNTS + e] : 0;
  int tiles = (c + BM - 1) / BM;
  if (tiles < 1) tiles = 1;
  int ov = tiles - 1;                 // overflow tiles (normally 0)
  int q = e & 7, s = (e >> 3) & 3;
  int ovs[4];
#pragma unroll
  for (int t = 0; t < 4; ++t) ovs[t] = __shfl(ov, q + 8 * t, 64);
  int pre = 0, tot = 0;
#pragma unroll
  for (int t = 0; t < 4; ++t) { if (t < s) pre += ovs[t]; tot += ovs[t]; }
  if (e < E_N) {
    for (int nt = 0; nt < 8; ++nt)
      ws[WS_QUEUE + q * 512 + s * 8 + nt] = (e << 8) | nt;
    int off = 32 + pre * 8;
    for (int mt = 1; mt < tiles; ++mt)
      for (int nt = 0; nt < 8; ++nt)
        ws[WS_QUEUE + q * 512 + off + (mt - 1) * 8 + nt] = (e << 8) | (mt << 3) | nt;
    if (s == 0) ws[WS_QLEN + q] = 32 + tot * 8;
  }
}

// ---------------- kernel 3: persistent grouped GEMM ----------------
// Each block: read own XCC_ID, pop item from that XCD's queue (steal if empty).
// Item = 320 rows (gathered, bf16) x 128 cols of one expert, full K.
// A: uint4 copy from featb (no conversion). W: f32 reg-staged -> bf16 LDS.
// Reg prefetch + LDS dbuf, 1 barrier per K-step (proven R5 pattern).
__global__ __launch_bounds__(THREADS, 1)
void k_gemm(const unsigned short* __restrict__ featb, const float* __restrict__ Wm,
            const float* __restrict__ bias, int* __restrict__ ws,
            float* __restrict__ out) {
  __shared__ uint4 lds4[2 * BUFSTRIDE];   // 112KB
  __shared__ int gids[BM];
  __shared__ int item_s;

  int tid  = threadIdx.x;
  int lane = tid & 63;
  int wv   = tid >> 6;
  int wm   = wv >> 1;   // 0..3  (80-row stripes)
  int wn   = wv & 1;    // 0..1  (64-col stripes)

  // fragment read indices (fixed across items)
  int aidx[5][2], bidx[4][2];
#pragma unroll
  for (int mi = 0; mi < 5; ++mi) {
    int r = wm * 80 + mi * 16 + (lane & 15);
#pragma unroll
    for (int ks = 0; ks < 2; ++ks)
      aidx[mi][ks] = r * 8 + ((ks * 4 + (lane >> 4)) ^ (r & 7));
  }
#pragma unroll
  for (int ni = 0; ni < 4; ++ni) {
    int r = wn * 64 + ni * 16 + (lane & 15);
#pragma unroll
    for (int ks = 0; ks < 2; ++ks)
      bidx[ni][ks] = WBASE + r * 8 + ((ks * 4 + (lane >> 4)) ^ (r & 7));
  }

  // A staging geometry: 5 slots/thread, slot l = tid + 512*i
  int arow[5], aphy[5];
#pragma unroll
  for (int i = 0; i < 5; ++i) {
    int l = tid + 512 * i;
    arow[i] = l >> 3;
    int seg = l & 7;
    aphy[i] = arow[i] * 8 + (seg ^ (arow[i] & 7));
  }
  // W staging geometry: row = tid>>2, quarter = tid&3 (16 floats)
  int wrow = tid >> 2, wq = tid & 3;
  int wphy0 = WBASE + wrow * 8 + ((2 * wq) ^ (wrow & 7));
  int wphy1 = WBASE + wrow * 8 + ((2 * wq + 1) ^ (wrow & 7));

  while (true) {
    // ---- pop one item with XCD affinity ----
    if (tid == 0) {
      int xcc = (int)(__builtin_amdgcn_s_getreg(XCC_ENC)) & 7;
      int it = -1;
      for (int t8 = 0; t8 < 8; ++t8) {
        int q = (xcc + t8) & 7;
        int idx = atomicAdd(&ws[WS_QCUR + q], 1);
        if (idx < ws[WS_QLEN + q]) { it = ws[WS_QUEUE + q * 512 + idx]; break; }
      }
      item_s = it;
    }
    __syncthreads();
    int item = item_s;
    if (item < 0) return;
    int e  = item >> 8;
    int mt = (item >> 3) & 31;
    int nt = item & 7;
    int count = ws[WS_COUNTS + e];
    int m0 = mt * BM;

    // ---- load gids ----
    if (tid < BM) {
      int gr = m0 + tid;
      gids[tid] = (gr < count) ? ws[WS_LISTS + e * B_N + gr] : -1;
    }
    __syncthreads();

    // ---- per-item source pointers ----
    const unsigned short* asrc[5];
#pragma unroll
    for (int i = 0; i < 5; ++i) {
      int g = gids[arow[i]];
      g = (g >= 0) ? (g >> 2) : 0;
      asrc[i] = featb + (size_t)g * IN_N + (tid + 512 * i & 7) * 8;
    }
    const float* wp = Wm + ((size_t)e * OUT_N + (size_t)(nt * BN + wrow)) * IN_N + wq * 16;

    uint4 ra[5];
    f32x4 rw[4];
    f32x4 acc[5][4] = {};

#define LOADK(KT)                                                            \
    do {                                                                     \
      _Pragma("unroll")                                                      \
      for (int i = 0; i < 5; ++i) ra[i] = *(const uint4*)(asrc[i] + (KT) * BK); \
      _Pragma("unroll")                                                      \
      for (int i = 0; i < 4; ++i) rw[i] = *(const f32x4*)(wp + (size_t)(KT) * BK + i * 4); \
    } while (0)

#define WRITEK(BUF)                                                          \
    do {                                                                     \
      _Pragma("unroll")                                                      \
      for (int i = 0; i < 5; ++i) lds4[(BUF) * BUFSTRIDE + aphy[i]] = ra[i]; \
      lds4[(BUF) * BUFSTRIDE + wphy0] = pack8(rw[0], rw[1]);                 \
      lds4[(BUF) * BUFSTRIDE + wphy1] = pack8(rw[2], rw[3]);                 \
    } while (0)

    LOADK(0);
    WRITEK(0);
    __syncthreads();

    int cur = 0;
#pragma unroll 1
    for (int kt = 0; kt < NKT; ++kt) {
      bool pf = (kt + 1 < NKT);
      if (pf) LOADK(kt + 1);

      int base = cur * BUFSTRIDE;
#pragma unroll
      for (int ks = 0; ks < 2; ++ks) {
        bf16x8 af[5], bfr[4];
#pragma unroll
        for (int mi = 0; mi < 5; ++mi) af[mi] = as_frag(lds4[base + aidx[mi][ks]]);
#pragma unroll
        for (int ni = 0; ni < 4; ++ni) bfr[ni] = as_frag(lds4[base + bidx[ni][ks]]);
#pragma unroll
        for (int mi = 0; mi < 5; ++mi)
#pragma unroll
          for (int ni = 0; ni < 4; ++ni)
            acc[mi][ni] = __builtin_amdgcn_mfma_f32_16x16x32_bf16(af[mi], bfr[ni], acc[mi][ni], 0, 0, 0);
      }

      if (pf) WRITEK(cur ^ 1);
      __syncthreads();
      cur ^= 1;
    }

    // ---- store: D row=(lane>>4)*4+j, col=lane&15 ----
#pragma unroll
    for (int ni = 0; ni < 4; ++ni) {
      int col = nt * BN + wn * 64 + ni * 16 + (lane & 15);
      float bs = bias[e * OUT_N + col];
#pragma unroll
      for (int mi = 0; mi < 5; ++mi) {
#pragma unroll
        for (int j2 = 0; j2 < 4; ++j2) {
          int g = gids[wm * 80 + mi * 16 + (lane >> 4) * 4 + j2];
          if (g >= 0) out[(size_t)g * OUT_N + col] = acc[mi][ni][j2] + bs;
        }
      }
    }
    __syncthreads();   // protect gids/item_s before next pop
  }
}

extern "C" void kernel_launch(void* const* d_in, const int* in_sizes, int n_in,
                              void* d_out, int out_size, void* d_ws, size_t ws_size,
                              hipStream_t stream) {
  const float* feat = (const float*)d_in[0];   // [B, IN]
  const float* Wm   = (const float*)d_in[1];   // [E, OUT, IN]
  const float* bias = (const float*)d_in[2];   // [E, OUT]
  const float* act  = (const float*)d_in[3];   // [B, E]
  int*   ws  = (int*)d_ws;
  unsigned short* featb = (unsigned short*)((char*)d_ws + FEATB_OFF);
  float* out = (float*)d_out;

  hipLaunchKernelGGL(k_zero,  dim3(1),                 dim3(64),      0, stream, ws);
  hipLaunchKernelGGL(k_conv,  dim3(B_N * IN_N / 2048), dim3(256),     0, stream, feat, featb);
  hipLaunchKernelGGL(k_topk,  dim3(B_N / 256),         dim3(256),     0, stream, act, ws);
  hipLaunchKernelGGL(k_tiles, dim3(1),                 dim3(64),      0, stream, ws);
  hipLaunchKernelGGL(k_gemm,  dim3(GRID_GEMM),         dim3(THREADS), 0, stream,
                     featb, Wm, bias, ws, out);
}